// Round 6
// baseline (731.483 us; speedup 1.0000x reference)
//
#include <hip/hip_runtime.h>
#include <math.h>

#define NROWS 8192
#define DIM   1024
#define KDIM  1024           // GEMM K dimension (pure-bf16 hi)
#define KSEL  5
#define TOPK  6
#define QB    256            // queries per block
#define KBB   256            // keys per block
#define NKB   (NROWS / KBB)  // key blocks = 32 (also lists per row)
#define NQB   (NROWS / QB)   // query blocks = 32
#define NT    (KDIM / 64)    // K-tiles = 16
#define PS    51             // mbuf per-query stride in float2 (pad 48->51)

typedef __attribute__((ext_vector_type(8))) short bf16x8;
typedef __attribute__((ext_vector_type(4))) float f32x4;

// ---------------------------------------------------------------------------
// ws layout:
//   [0]          : int match counter   [4] : int done counter (memset 8 B)
//   [256]        : Q2 bf16[8192][1024]  (hi only, XOR-swizzled)   16 MB
//   [+16M]       : K2 bf16[8192][1024]  (hi only, XOR-swizzled)   16 MB
//   [+32M]       : partials float2[8192][32][6]  (12.6 MB)
//
// Round-21 = Round-20 resubmitted (r5 bench was an infra failure; audit
// found no hang/fault path: all barriers converged, all accesses in
// bounds, global-direct B layout verified equivalent).
//
// Round-20: B-operand direct global->register + wave-per-row prep.
//   r17/r18/r19 (2-phase dbuf / counted vmcnt / 8-phase interleave) ALL
//   neutral (235-257) -> K-loop schedule is not the constraint. Counters:
//   dur == hbm_bytes / ~480 GB/s in every variant (6% HBM peak), occupancy
//   reg-capped at 2 waves/SIMD (128 AGPR acc + ~95 VGPR), K-scaling shows
//   ~127 us K-independent overhead. Suspect: every A AND B byte flows
//   global->L2/LLC->LDS->reg through the drained staging pipe.
//   Change: Q fragments load straight global->VGPR (pre-swizzled global
//   layout => same fragment address formula as the LDS read), double-
//   buffered one tile ahead in regs. Halves global_load_lds drain volume,
//   removes 1/3 of LDS reads and all Q LDS-writes; LDS 128->64 KB.
//   prep: wave-per-row, no syncthreads, 4096 x 256.
//   Predict: gemm ~185-210 us, MfmaUtil 29-33, total ~295-315.
//   If gemm >= 225: transport-bound confirmed -> next round halves bytes.
// ---------------------------------------------------------------------------

__device__ __forceinline__ unsigned short f2bf(float x) {
    unsigned u = __float_as_uint(x);
    unsigned r = (u + 0x7fffu + ((u >> 16) & 1u)) >> 16;   // RNE
    return (unsigned short)r;
}

// full tie-break compare (merge paths — arbitrary id order there)
__device__ __forceinline__ bool better(float v, int id, float v2, int id2) {
    return (v > v2) || (v == v2 && id < id2);
}
__device__ __forceinline__ void insert6(float v, int id, float* tv, int* ti) {
    if (!better(v, id, tv[TOPK - 1], ti[TOPK - 1])) return;
    int j = TOPK - 1;
    while (j > 0 && better(v, id, tv[j - 1], ti[j - 1])) {
        tv[j] = tv[j - 1]; ti[j] = ti[j - 1]; --j;
    }
    tv[j] = v; ti[j] = id;
}

// branchless strict insert (ascending-id stream => strict '>' is exact).
__device__ __forceinline__ void ins6(float v, int id, float* tv, int* ti) {
    if (v <= tv[5]) return;
    bool gt[6];
#pragma unroll
    for (int j = 0; j < 6; ++j) gt[j] = v > tv[j];
#pragma unroll
    for (int j = 5; j >= 1; --j)
        if (gt[j - 1]) { tv[j] = tv[j - 1]; ti[j] = ti[j - 1]; }
    if (gt[0]) { tv[0] = v; ti[0] = id; }
#pragma unroll
    for (int j = 1; j < 6; ++j)
        if (gt[j] && !gt[j - 1]) { tv[j] = v; ti[j] = id; }
}

__device__ __forceinline__ void async16(const unsigned short* g, unsigned short* l) {
    __builtin_amdgcn_global_load_lds(
        (const __attribute__((address_space(1))) void*)g,
        (__attribute__((address_space(3))) void*)l, 16, 0, 0);
}

// --- 1) normalize -> bf16 (hi only), wave-per-row, no block sync ------------
// Same output layout as before: chunk t (t=0..127) = elems {4t..4t+3,
// 512+4t..512+4t+3} stored as 8-group at (t>>3)*64 + ((t&7)^(r&7))*8.
// Lane l handles chunks l and l+64.
__global__ __launch_bounds__(256) void prep_kernel(
        const float* __restrict__ q, const float* __restrict__ kb,
        unsigned short* __restrict__ Q2, unsigned short* __restrict__ K2) {
    const int w = threadIdx.x >> 6, lane = threadIdx.x & 63;
    const int b = blockIdx.x * 4 + w;    // row 0..16383
    const bool isQ = (b < NROWS);
    const int r = isQ ? b : b - NROWS;
    const float* src = (isQ ? q : kb) + (size_t)r * DIM;
    unsigned short* D = (isQ ? Q2 : K2) + (size_t)r * KDIM;

    float4 v[4];
#pragma unroll
    for (int i = 0; i < 4; ++i)
        v[i] = *(const float4*)(src + i * 256 + lane * 4);   // coalesced

    float s = 0.f;
#pragma unroll
    for (int i = 0; i < 4; ++i)
        s += v[i].x * v[i].x + v[i].y * v[i].y + v[i].z * v[i].z + v[i].w * v[i].w;
    for (int o = 32; o; o >>= 1) s += __shfl_down(s, o, 64);
    s = __shfl(s, 0, 64);                 // broadcast row sum
    const float inv = 1.0f / fmaxf(sqrtf(s), 1e-12f);

    // chunk l = {v[0], v[2]}, chunk l+64 = {v[1], v[3]}
    bf16x8 g0, g1;
    g0[0] = (short)f2bf(v[0].x * inv); g0[1] = (short)f2bf(v[0].y * inv);
    g0[2] = (short)f2bf(v[0].z * inv); g0[3] = (short)f2bf(v[0].w * inv);
    g0[4] = (short)f2bf(v[2].x * inv); g0[5] = (short)f2bf(v[2].y * inv);
    g0[6] = (short)f2bf(v[2].z * inv); g0[7] = (short)f2bf(v[2].w * inv);
    g1[0] = (short)f2bf(v[1].x * inv); g1[1] = (short)f2bf(v[1].y * inv);
    g1[2] = (short)f2bf(v[1].z * inv); g1[3] = (short)f2bf(v[1].w * inv);
    g1[4] = (short)f2bf(v[3].x * inv); g1[5] = (short)f2bf(v[3].y * inv);
    g1[6] = (short)f2bf(v[3].z * inv); g1[7] = (short)f2bf(v[3].w * inv);

    const int perm = ((lane & 7) ^ (r & 7)) * 8;
    const int off0 = (lane >> 3) * 64 + perm;            // chunk l
    const int off1 = (8 + (lane >> 3)) * 64 + perm;      // chunk l+64
    *(bf16x8*)(D + off0) = g0;
    *(bf16x8*)(D + off1) = g1;
}

// --- 2) 256x256 GEMM: K via LDS dbuf, Q direct global->reg ------------------
__global__ __launch_bounds__(512, 2) void gemm_topk_kernel(
        const unsigned short* __restrict__ Q2, const unsigned short* __restrict__ K2,
        float2* __restrict__ partials) {
    // K dbuf: 2 x 32 KB; merge: mbuf 128*PS float2 (52 KB) aliased, 2 passes
    __shared__ __align__(16) char smem[65536];
    float2* mbuf = (float2*)smem;

    const int tid = threadIdx.x;         // 0..511 (8 waves)
    const int w = tid >> 6, l = tid & 63;
    const int l15 = l & 15, l4 = l >> 4;
    const int qbase = blockIdx.x * QB;
    const int kbase = blockIdx.y * KBB;
    const int wkh = w & 1;               // key half    (128 keys)
    const int wqh = w >> 1;              // query quart (64 queries)

    const int akoff = (tid & 7) * 8;     // swizzled position within k-block
    const int xr = l15 & 7;
    const int fa_row = (wkh * 128 + l15) * 64;   // + mt*1024

    const size_t kstage = (size_t)(kbase + (tid >> 3)) * KDIM + akoff;

    // B-fragment global element offsets (32-bit): qrow*1024 + p8(ks)
    unsigned qv[2][4];
#pragma unroll
    for (int ks = 0; ks < 2; ++ks)
#pragma unroll
        for (int nt = 0; nt < 4; ++nt) {
            const int qrow = qbase + wqh * 64 + nt * 16 + l15;
            qv[ks][nt] = (unsigned)qrow * KDIM + (unsigned)(((ks * 4 + l4) ^ xr) * 8);
        }

    f32x4 acc[8][4];   // [mt = key-tile][nt = query-tile]
#pragma unroll
    for (int mt = 0; mt < 8; ++mt)
#pragma unroll
        for (int nt = 0; nt < 4; ++nt) acc[mt][nt] = (f32x4){0.f, 0.f, 0.f, 0.f};

    unsigned short* Kb0 = (unsigned short*)smem;
    unsigned short* Kb1 = (unsigned short*)(smem + 32768);

    bf16x8 b0[2][4], b1[2][4];           // B frags: tiles t (cur) / t+1 (next)

    // ---- prologue: stage K(0) -> buf0; load B(0) -> b0 --------------------
#pragma unroll
    for (int j = 0; j < 4; ++j)
        async16(K2 + kstage + (size_t)j * 64 * KDIM, Kb0 + (tid + j * 512) * 8);
#pragma unroll
    for (int ks = 0; ks < 2; ++ks)
#pragma unroll
        for (int nt = 0; nt < 4; ++nt)
            b0[ks][nt] = *(const bf16x8*)(Q2 + qv[ks][nt]);
    __syncthreads();   // drains vmcnt: buf0 + b0 ready

#define STEP(TT, CURBUF, NXTBUF, BC, BN)                                      \
    {                                                                         \
        const int tt = (TT);                                                  \
        if (tt + 1 < NT) {                                                    \
            const size_t nk0 = (size_t)(tt + 1) * 64;                         \
            _Pragma("unroll")                                                 \
            for (int j = 0; j < 4; ++j)                                       \
                async16(K2 + kstage + (size_t)j * 64 * KDIM + nk0,            \
                        (NXTBUF) + (tid + j * 512) * 8);                      \
            _Pragma("unroll")                                                 \
            for (int ks = 0; ks < 2; ++ks)                                    \
                _Pragma("unroll")                                             \
                for (int nt = 0; nt < 4; ++nt)                                \
                    (BN)[ks][nt] = *(const bf16x8*)(Q2 + qv[ks][nt] +         \
                                                    (unsigned)(tt + 1) * 64); \
        }                                                                     \
        _Pragma("unroll")                                                     \
        for (int ks = 0; ks < 2; ++ks) {                                      \
            const int p8 = ((ks * 4 + l4) ^ xr) * 8;                          \
            bf16x8 af[4];                                                     \
            _Pragma("unroll")                                                 \
            for (int m = 0; m < 4; ++m)                                       \
                af[m] = *(const bf16x8*)((CURBUF) + fa_row + m * 1024 + p8);  \
            __builtin_amdgcn_s_setprio(1);                                    \
            _Pragma("unroll")                                                 \
            for (int m = 0; m < 4; ++m)                                       \
                _Pragma("unroll")                                             \
                for (int nt = 0; nt < 4; ++nt)                                \
                    acc[m][nt] = __builtin_amdgcn_mfma_f32_16x16x32_bf16(     \
                        af[m], (BC)[ks][nt], acc[m][nt], 0, 0, 0);            \
            __builtin_amdgcn_s_setprio(0);                                    \
            _Pragma("unroll")                                                 \
            for (int m = 0; m < 4; ++m)                                       \
                af[m] = *(const bf16x8*)((CURBUF) + fa_row + (m + 4) * 1024 + p8); \
            __builtin_amdgcn_s_setprio(1);                                    \
            _Pragma("unroll")                                                 \
            for (int m = 0; m < 4; ++m)                                       \
                _Pragma("unroll")                                             \
                for (int nt = 0; nt < 4; ++nt)                                \
                    acc[m + 4][nt] = __builtin_amdgcn_mfma_f32_16x16x32_bf16( \
                        af[m], (BC)[ks][nt], acc[m + 4][nt], 0, 0, 0);        \
            __builtin_amdgcn_s_setprio(0);                                    \
        }                                                                     \
        __syncthreads();   /* drains vmcnt: K(tt+1) in LDS, BN arrived */     \
    }

#pragma unroll 1
    for (int t2 = 0; t2 < NT; t2 += 2) {
        STEP(t2,     Kb0, Kb1, b0, b1);
        STEP(t2 + 1, Kb1, Kb0, b1, b0);
    }
#undef STEP

    // ---- in-register top-6 (once per block): 32 keys/thread per nt-list ----
    float tvl[4][6]; int til[4][6];
#pragma unroll
    for (int n = 0; n < 4; ++n)
#pragma unroll
        for (int i = 0; i < 6; ++i) { tvl[n][i] = -INFINITY; til[n][i] = 0x7fffffff; }

#pragma unroll
    for (int nt = 0; nt < 4; ++nt) {
#pragma unroll
        for (int mt = 0; mt < 8; ++mt) {
            const f32x4 a = acc[mt][nt];
            const float m4 = fmaxf(fmaxf(a.x, a.y), fmaxf(a.z, a.w));
            if (m4 > tvl[nt][5]) {
                const int kk = kbase + wkh * 128 + mt * 16 + l4 * 4;
                ins6(a.x, kk + 0, tvl[nt], til[nt]);
                ins6(a.y, kk + 1, tvl[nt], til[nt]);
                ins6(a.z, kk + 2, tvl[nt], til[nt]);
                ins6(a.w, kk + 3, tvl[nt], til[nt]);
            }
        }
    }

    // ---- block merge: 8 slots/query, two half-passes (mbuf = 52 KB) -------
    const int slot = wkh * 4 + l4;       // 0..7
#pragma unroll 1
    for (int h = 0; h < 2; ++h) {
        if ((wqh >> 1) == h) {           // waves owning queries h*128..h*128+127
#pragma unroll
            for (int nt = 0; nt < 4; ++nt) {
                const int ql = (wqh & 1) * 64 + nt * 16 + l15;   // 0..127
                float2* dst = mbuf + (size_t)ql * PS + slot * 6;
#pragma unroll
                for (int e = 0; e < 6; ++e)
                    dst[e] = make_float2(tvl[nt][e], __int_as_float(til[nt][e]));
            }
        }
        __syncthreads();
        if (tid < 128) {                 // one thread per query merges 8 lists
            float tv[6]; int ti[6];
#pragma unroll
            for (int i = 0; i < 6; ++i) { tv[i] = -INFINITY; ti[i] = 0x7fffffff; }
            const float2* src = mbuf + (size_t)tid * PS;
            for (int e = 0; e < 48; ++e) {
                float2 p = src[e];
                if (p.x < tv[5]) continue;
                insert6(p.x, __float_as_int(p.y), tv, ti);
            }
            size_t off = ((size_t)(qbase + h * 128 + tid) * NKB + blockIdx.y) * TOPK;
#pragma unroll
            for (int i = 0; i < 6; ++i)
                partials[off + i] = make_float2(tv[i], __int_as_float(ti[i]));
        }
        __syncthreads();
    }
}

// --- 3) parallel merge + fused finalize (device-scope handoff) --------------
__global__ __launch_bounds__(256) void merge_kernel(
        const float2* __restrict__ partials,
        const int* __restrict__ query_ids, const int* __restrict__ key_ids,
        int* __restrict__ counter, int* __restrict__ done,
        float* __restrict__ out) {
    __shared__ float2 lbuf[32][49];      // [row-in-block][8 parts * 6, pad 49]
    __shared__ int sc[32];
    const int tid  = threadIdx.x;
    const int rloc = tid >> 3;           // 0..31
    const int part = tid & 7;            // 0..7
    const int row  = blockIdx.x * 32 + rloc;

    // stage 1: each thread merges 4 of the 32 lists (24 entries, coalesced)
    float tv[6]; int ti[6];
#pragma unroll
    for (int i = 0; i < 6; ++i) { tv[i] = -INFINITY; ti[i] = 0x7fffffff; }
    const float2* src = partials + ((size_t)row * NKB + part * 4) * TOPK;
#pragma unroll
    for (int e = 0; e < 24; ++e) {
        float2 p = src[e];
        if (p.x < tv[5]) continue;
        insert6(p.x, __float_as_int(p.y), tv, ti);
    }
#pragma unroll
    for (int i = 0; i < 6; ++i)
        lbuf[rloc][part * 6 + i] = make_float2(tv[i], __int_as_float(ti[i]));
    __syncthreads();

    // stage 2: one thread per row merges the 8 partial lists + counts
    if (part == 0) {
        float tv2[6]; int ti2[6];
#pragma unroll
        for (int i = 0; i < 6; ++i) { tv2[i] = -INFINITY; ti2[i] = 0x7fffffff; }
#pragma unroll
        for (int e = 0; e < 48; ++e) {
            float2 p = lbuf[rloc][e];
            if (p.x < tv2[5]) continue;
            insert6(p.x, __float_as_int(p.y), tv2, ti2);
        }
        const int qid = query_ids[row];
        int cnt = 0;
#pragma unroll
        for (int r = 1; r < TOPK; ++r)
            cnt += (key_ids[ti2[r]] == qid) ? 1 : 0;
        sc[rloc] = cnt;
    }
    __syncthreads();
    if (tid == 0) {
        int c = 0;
#pragma unroll
        for (int i = 0; i < 32; ++i) c += sc[i];
        atomicAdd(counter, c);
        __threadfence();                 // counter-add visible before done-add
        int prev = atomicAdd(done, 1);
        if (prev == gridDim.x - 1) {     // last block finalizes
            int total = atomicAdd(counter, 0);   // coherent read
            out[0] = (float)total / (float)(NROWS * KSEL);
        }
    }
}

extern "C" void kernel_launch(void* const* d_in, const int* in_sizes, int n_in,
                              void* d_out, int out_size, void* d_ws, size_t ws_size,
                              hipStream_t stream) {
    (void)in_sizes; (void)n_in; (void)out_size; (void)ws_size;
    const int*   query_ids = (const int*)d_in[0];
    const int*   key_ids   = (const int*)d_in[1];
    const float* q         = (const float*)d_in[2];
    const float* kb        = (const float*)d_in[3];

    char* ws = (char*)d_ws;
    const size_t MB16 = (size_t)NROWS * KDIM * sizeof(unsigned short);  // 16 MB
    int*            counter  = (int*)ws;          // [0]=matches, [1]=done
    unsigned short* Q2       = (unsigned short*)(ws + 256);
    unsigned short* K2       = (unsigned short*)(ws + 256 + MB16);
    float2*         partials = (float2*)(ws + 256 + 2 * MB16);

    hipMemsetAsync(counter, 0, 2 * sizeof(int), stream);
    prep_kernel<<<(2 * NROWS) / 4, 256, 0, stream>>>(q, kb, Q2, K2);
    gemm_topk_kernel<<<dim3(NQB, NKB), 512, 0, stream>>>(Q2, K2, partials);
    merge_kernel<<<NROWS / 32, 256, 0, stream>>>(partials, query_ids, key_ids,
                                                 counter, counter + 1,
                                                 (float*)d_out);
}

// Round 7
// 367.160 us; speedup vs baseline: 1.9923x; 1.9923x over previous
//
#include <hip/hip_runtime.h>
#include <math.h>

#define NROWS 8192
#define DIM   1024
#define KDIM  1024           // GEMM K dimension (pure-bf16 hi)
#define KSEL  5
#define TOPK  6
#define QB    128            // queries per block
#define KBB   256            // keys per block
#define NKB   (NROWS / KBB)  // key blocks = 32 (also lists per row)
#define NQB   (NROWS / QB)   // query blocks = 64
#define NT    (KDIM / 64)    // K-steps = 16
#define PS    51             // mbuf per-query stride in float2 (pad 48->51)

typedef __attribute__((ext_vector_type(8))) short bf16x8;
typedef __attribute__((ext_vector_type(4))) float f32x4;

// ---------------------------------------------------------------------------
// ws layout:
//   [0]   : int match counter   [4] : int done counter (memset 8 B)
//   [256] : Q2 bf16[8192][1024] (row-XOR-preswizzled)  16 MB
//   [+16M]: K2 bf16[8192][1024] (row-XOR-preswizzled)  16 MB
//   [+32M]: partials float2[8192][32][6]               12.6 MB
//
// Round-22: ZERO-LDS, ZERO-BARRIER K-loop (both operands global->VGPR).
//   Ledger: r16-r19 proved schedule/latency/intensity changes are ALL
//   neutral (235-257 us); r20/r21 B-direct spilled (WRITE_SIZE 661 MB --
//   64 persistent dbuf VGPRs on top of 128 acc blew the budget) but its
//   1.6 TB/s proves ~480 GB/s was never a memory-service ceiling, and its
//   absmax=0 validated direct-from-preswizzled-global fragment addressing.
//   The one invariant across all neutral variants: the global_load_lds +
//   vmcnt-drain + barrier machinery. This round deletes it: per ks-half,
//   12 global_load_dwordx4 -> consumed by 32 MFMAs in the same half (no
//   persistent frag buffers; ~190 regs, 2 waves/SIMD, no spill). A-frags
//   L1-reused by 4 waves, B by 2; panels L2-resident. No __syncthreads in
//   the K-loop at all.
//   Sentinel: WRITE_SIZE ~13 MB (else spill -> reject). Predict gemm
//   ~100-160 us, MfmaUtil 40-60%; if ~230 flat, cost is epilogue/overhead
//   (isolated for r8).
// ---------------------------------------------------------------------------

__device__ __forceinline__ unsigned short f2bf(float x) {
    unsigned u = __float_as_uint(x);
    unsigned r = (u + 0x7fffu + ((u >> 16) & 1u)) >> 16;   // RNE
    return (unsigned short)r;
}

// full tie-break compare (merge paths — arbitrary id order there)
__device__ __forceinline__ bool better(float v, int id, float v2, int id2) {
    return (v > v2) || (v == v2 && id < id2);
}
__device__ __forceinline__ void insert6(float v, int id, float* tv, int* ti) {
    if (!better(v, id, tv[TOPK - 1], ti[TOPK - 1])) return;
    int j = TOPK - 1;
    while (j > 0 && better(v, id, tv[j - 1], ti[j - 1])) {
        tv[j] = tv[j - 1]; ti[j] = ti[j - 1]; --j;
    }
    tv[j] = v; ti[j] = id;
}

// branchless strict insert (ascending-id stream => strict '>' is exact).
__device__ __forceinline__ void ins6(float v, int id, float* tv, int* ti) {
    if (v <= tv[5]) return;
    bool gt[6];
#pragma unroll
    for (int j = 0; j < 6; ++j) gt[j] = v > tv[j];
#pragma unroll
    for (int j = 5; j >= 1; --j)
        if (gt[j - 1]) { tv[j] = tv[j - 1]; ti[j] = ti[j - 1]; }
    if (gt[0]) { tv[0] = v; ti[0] = id; }
#pragma unroll
    for (int j = 1; j < 6; ++j)
        if (gt[j] && !gt[j - 1]) { tv[j] = v; ti[j] = id; }
}

// --- 1) normalize -> bf16 (hi only), wave-per-row, no block sync ------------
// Output layout (unchanged): chunk t (t=0..127) = elems {4t..4t+3,
// 512+4t..512+4t+3} stored as 8-group at (t>>3)*64 + ((t&7)^(r&7))*8.
// Lane l handles chunks l and l+64.  (validated absmax=0 in r6)
__global__ __launch_bounds__(256) void prep_kernel(
        const float* __restrict__ q, const float* __restrict__ kb,
        unsigned short* __restrict__ Q2, unsigned short* __restrict__ K2) {
    const int w = threadIdx.x >> 6, lane = threadIdx.x & 63;
    const int b = blockIdx.x * 4 + w;    // row 0..16383
    const bool isQ = (b < NROWS);
    const int r = isQ ? b : b - NROWS;
    const float* src = (isQ ? q : kb) + (size_t)r * DIM;
    unsigned short* D = (isQ ? Q2 : K2) + (size_t)r * KDIM;

    float4 v[4];
#pragma unroll
    for (int i = 0; i < 4; ++i)
        v[i] = *(const float4*)(src + i * 256 + lane * 4);   // coalesced

    float s = 0.f;
#pragma unroll
    for (int i = 0; i < 4; ++i)
        s += v[i].x * v[i].x + v[i].y * v[i].y + v[i].z * v[i].z + v[i].w * v[i].w;
    for (int o = 32; o; o >>= 1) s += __shfl_down(s, o, 64);
    s = __shfl(s, 0, 64);                 // broadcast row sum
    const float inv = 1.0f / fmaxf(sqrtf(s), 1e-12f);

    bf16x8 g0, g1;
    g0[0] = (short)f2bf(v[0].x * inv); g0[1] = (short)f2bf(v[0].y * inv);
    g0[2] = (short)f2bf(v[0].z * inv); g0[3] = (short)f2bf(v[0].w * inv);
    g0[4] = (short)f2bf(v[2].x * inv); g0[5] = (short)f2bf(v[2].y * inv);
    g0[6] = (short)f2bf(v[2].z * inv); g0[7] = (short)f2bf(v[2].w * inv);
    g1[0] = (short)f2bf(v[1].x * inv); g1[1] = (short)f2bf(v[1].y * inv);
    g1[2] = (short)f2bf(v[1].z * inv); g1[3] = (short)f2bf(v[1].w * inv);
    g1[4] = (short)f2bf(v[3].x * inv); g1[5] = (short)f2bf(v[3].y * inv);
    g1[6] = (short)f2bf(v[3].z * inv); g1[7] = (short)f2bf(v[3].w * inv);

    const int perm = ((lane & 7) ^ (r & 7)) * 8;
    const int off0 = (lane >> 3) * 64 + perm;            // chunk l
    const int off1 = (8 + (lane >> 3)) * 64 + perm;      // chunk l+64
    *(bf16x8*)(D + off0) = g0;
    *(bf16x8*)(D + off1) = g1;
}

// --- 2) 256x128 GEMM, both operands direct global->reg, no LDS in K-loop ----
__global__ __launch_bounds__(256, 2) void gemm_topk_kernel(
        const unsigned short* __restrict__ Q2, const unsigned short* __restrict__ K2,
        float2* __restrict__ partials) {
    __shared__ float2 mbuf[128 * PS];    // merge buffer only (52 KB)

    const int tid = threadIdx.x;         // 0..255 (4 waves)
    const int w = tid >> 6, l = tid & 63;
    const int l15 = l & 15, l4 = l >> 4;
    const int qbase = blockIdx.x * QB;
    const int kbase = blockIdx.y * KBB;
    const int wkh = w & 1;               // key half   (128 keys)
    const int wqh = w >> 1;              // query half (64 queries)
    const int xr = l15 & 7;

    // fragment global element offsets (fits 32-bit: max 8192*1024)
    const unsigned kof = (unsigned)(kbase + wkh * 128 + l15) * KDIM;
    unsigned qof[4];
#pragma unroll
    for (int nt = 0; nt < 4; ++nt)
        qof[nt] = (unsigned)(qbase + wqh * 64 + nt * 16 + l15) * KDIM;
    const unsigned pe0 = (unsigned)((l4 ^ xr) * 8);
    const unsigned pe1 = (unsigned)(((4 + l4) ^ xr) * 8);

    f32x4 acc[8][4];   // [mt = key-tile][nt = query-tile]
#pragma unroll
    for (int mt = 0; mt < 8; ++mt)
#pragma unroll
        for (int nt = 0; nt < 4; ++nt) acc[mt][nt] = (f32x4){0.f, 0.f, 0.f, 0.f};

#pragma unroll 1
    for (int t = 0; t < NT; ++t) {
        const unsigned tb = (unsigned)t * 64u;
#pragma unroll 1
        for (int ks = 0; ks < 2; ++ks) {
            const unsigned pk = tb + (ks ? pe1 : pe0);
            bf16x8 bq[4];
#pragma unroll
            for (int nt = 0; nt < 4; ++nt)
                bq[nt] = *(const bf16x8*)(Q2 + qof[nt] + pk);
            bf16x8 af[8];
#pragma unroll
            for (int mt = 0; mt < 8; ++mt)
                af[mt] = *(const bf16x8*)(K2 + kof + (unsigned)mt * (16u * KDIM) + pk);
            __builtin_amdgcn_s_setprio(1);
#pragma unroll
            for (int mt = 0; mt < 8; ++mt)
#pragma unroll
                for (int nt = 0; nt < 4; ++nt)
                    acc[mt][nt] = __builtin_amdgcn_mfma_f32_16x16x32_bf16(
                        af[mt], bq[nt], acc[mt][nt], 0, 0, 0);
            __builtin_amdgcn_s_setprio(0);
        }
    }

    // ---- in-register top-6: 32 keys/thread per nt-list --------------------
    float tvl[4][6]; int til[4][6];
#pragma unroll
    for (int n = 0; n < 4; ++n)
#pragma unroll
        for (int i = 0; i < 6; ++i) { tvl[n][i] = -INFINITY; til[n][i] = 0x7fffffff; }

#pragma unroll
    for (int nt = 0; nt < 4; ++nt) {
#pragma unroll
        for (int mt = 0; mt < 8; ++mt) {
            const f32x4 a = acc[mt][nt];
            const float m4 = fmaxf(fmaxf(a.x, a.y), fmaxf(a.z, a.w));
            if (m4 > tvl[nt][5]) {
                const int kk = kbase + wkh * 128 + mt * 16 + l4 * 4;
                ins6(a.x, kk + 0, tvl[nt], til[nt]);
                ins6(a.y, kk + 1, tvl[nt], til[nt]);
                ins6(a.z, kk + 2, tvl[nt], til[nt]);
                ins6(a.w, kk + 3, tvl[nt], til[nt]);
            }
        }
    }

    // ---- block merge: 8 slots per query -> 1 list per query ---------------
    const int slot = wkh * 4 + l4;       // 0..7
#pragma unroll
    for (int nt = 0; nt < 4; ++nt) {
        const int ql = wqh * 64 + nt * 16 + l15;     // local query 0..127
        float2* dst = mbuf + (size_t)ql * PS + slot * 6;
#pragma unroll
        for (int e = 0; e < 6; ++e)
            dst[e] = make_float2(tvl[nt][e], __int_as_float(til[nt][e]));
    }
    __syncthreads();

    if (tid < 128) {                     // one thread per query merges 8 lists
        float tv[6]; int ti[6];
#pragma unroll
        for (int i = 0; i < 6; ++i) { tv[i] = -INFINITY; ti[i] = 0x7fffffff; }
        const float2* src = mbuf + (size_t)tid * PS;
        for (int e = 0; e < 48; ++e) {
            float2 p = src[e];
            if (p.x < tv[5]) continue;
            insert6(p.x, __float_as_int(p.y), tv, ti);
        }
        size_t off = ((size_t)(qbase + tid) * NKB + blockIdx.y) * TOPK;
#pragma unroll
        for (int i = 0; i < 6; ++i)
            partials[off + i] = make_float2(tv[i], __int_as_float(ti[i]));
    }
}

// --- 3) parallel merge + fused finalize (device-scope handoff) --------------
__global__ __launch_bounds__(256) void merge_kernel(
        const float2* __restrict__ partials,
        const int* __restrict__ query_ids, const int* __restrict__ key_ids,
        int* __restrict__ counter, int* __restrict__ done,
        float* __restrict__ out) {
    __shared__ float2 lbuf[32][49];      // [row-in-block][8 parts * 6, pad 49]
    __shared__ int sc[32];
    const int tid  = threadIdx.x;
    const int rloc = tid >> 3;           // 0..31
    const int part = tid & 7;            // 0..7
    const int row  = blockIdx.x * 32 + rloc;

    // stage 1: each thread merges 4 of the 32 lists (24 entries, coalesced)
    float tv[6]; int ti[6];
#pragma unroll
    for (int i = 0; i < 6; ++i) { tv[i] = -INFINITY; ti[i] = 0x7fffffff; }
    const float2* src = partials + ((size_t)row * NKB + part * 4) * TOPK;
#pragma unroll
    for (int e = 0; e < 24; ++e) {
        float2 p = src[e];
        if (p.x < tv[5]) continue;
        insert6(p.x, __float_as_int(p.y), tv, ti);
    }
#pragma unroll
    for (int i = 0; i < 6; ++i)
        lbuf[rloc][part * 6 + i] = make_float2(tv[i], __int_as_float(ti[i]));
    __syncthreads();

    // stage 2: one thread per row merges the 8 partial lists + counts
    if (part == 0) {
        float tv2[6]; int ti2[6];
#pragma unroll
        for (int i = 0; i < 6; ++i) { tv2[i] = -INFINITY; ti2[i] = 0x7fffffff; }
#pragma unroll
        for (int e = 0; e < 48; ++e) {
            float2 p = lbuf[rloc][e];
            if (p.x < tv2[5]) continue;
            insert6(p.x, __float_as_int(p.y), tv2, ti2);
        }
        const int qid = query_ids[row];
        int cnt = 0;
#pragma unroll
        for (int r = 1; r < TOPK; ++r)
            cnt += (key_ids[ti2[r]] == qid) ? 1 : 0;
        sc[rloc] = cnt;
    }
    __syncthreads();
    if (tid == 0) {
        int c = 0;
#pragma unroll
        for (int i = 0; i < 32; ++i) c += sc[i];
        atomicAdd(counter, c);
        __threadfence();                 // counter-add visible before done-add
        int prev = atomicAdd(done, 1);
        if (prev == gridDim.x - 1) {     // last block finalizes
            int total = atomicAdd(counter, 0);   // coherent read
            out[0] = (float)total / (float)(NROWS * KSEL);
        }
    }
}

extern "C" void kernel_launch(void* const* d_in, const int* in_sizes, int n_in,
                              void* d_out, int out_size, void* d_ws, size_t ws_size,
                              hipStream_t stream) {
    (void)in_sizes; (void)n_in; (void)out_size; (void)ws_size;
    const int*   query_ids = (const int*)d_in[0];
    const int*   key_ids   = (const int*)d_in[1];
    const float* q         = (const float*)d_in[2];
    const float* kb        = (const float*)d_in[3];

    char* ws = (char*)d_ws;
    const size_t MB16 = (size_t)NROWS * KDIM * sizeof(unsigned short);  // 16 MB
    int*            counter  = (int*)ws;          // [0]=matches, [1]=done
    unsigned short* Q2       = (unsigned short*)(ws + 256);
    unsigned short* K2       = (unsigned short*)(ws + 256 + MB16);
    float2*         partials = (float2*)(ws + 256 + 2 * MB16);

    hipMemsetAsync(counter, 0, 2 * sizeof(int), stream);
    prep_kernel<<<(2 * NROWS) / 4, 256, 0, stream>>>(q, kb, Q2, K2);
    gemm_topk_kernel<<<dim3(NQB, NKB), 256, 0, stream>>>(Q2, K2, partials);
    merge_kernel<<<NROWS / 32, 256, 0, stream>>>(partials, query_ids, key_ids,
                                                 counter, counter + 1,
                                                 (float*)d_out);
}